// Round 15
// baseline (174.297 us; speedup 1.0000x reference)
//
#include <hip/hip_runtime.h>
#include <hip/hip_bf16.h>
#include <stdint.h>

#define Bn 16384
#define Dd 1024
#define Hh 256
#define NBk 16

// d_out layout (all float32): x+out | y_logits | y_idx | y | z_mean | z_logvar | z
#define O1 ((size_t)Bn*Dd)
#define O2 (O1 + (size_t)Bn*NBk)
#define O3 (O2 + (size_t)Bn)
#define O4 (O3 + (size_t)Bn*NBk)
#define O5 (O4 + (size_t)Bn*NBk)
#define O6 (O5 + (size_t)Bn*NBk)

typedef __attribute__((ext_vector_type(8))) short s16x8;
typedef __attribute__((ext_vector_type(4))) float f32x4;

#define MFMA_BF16(a,b,c) __builtin_amdgcn_mfma_f32_16x16x32_bf16((a),(b),(c),0,0,0)

__device__ __forceinline__ float blo(unsigned v){ return __uint_as_float(v << 16); }
__device__ __forceinline__ float bhi(unsigned v){ return __uint_as_float(v & 0xFFFF0000u); }
__device__ __forceinline__ unsigned short f2b(float f){   // f32 -> bf16 RNE
  unsigned u = __float_as_uint(f);
  return (unsigned short)((u + 0x7FFFu + ((u >> 16) & 1u)) >> 16);
}
__device__ __forceinline__ s16x8 cvt8(const f32x4 u0, const f32x4 u1) {
  s16x8 v;
  v[0]=(short)f2b(u0[0]); v[1]=(short)f2b(u0[1]); v[2]=(short)f2b(u0[2]); v[3]=(short)f2b(u0[3]);
  v[4]=(short)f2b(u1[0]); v[5]=(short)f2b(u1[1]); v[6]=(short)f2b(u1[2]); v[7]=(short)f2b(u1[3]);
  return v;
}
// split 8 f32 into bf16 hi + bf16 lo (x ~= hi + lo to ~2^-18 rel)
__device__ __forceinline__ void split8(const f32x4 u0, const f32x4 u1, s16x8& hi, s16x8& lo) {
  #pragma unroll
  for (int e = 0; e < 4; ++e) {
    const unsigned short h = f2b(u0[e]);
    hi[e] = (short)h;
    lo[e] = (short)f2b(u0[e] - __uint_as_float((unsigned)h << 16));
  }
  #pragma unroll
  for (int e = 0; e < 4; ++e) {
    const unsigned short h = f2b(u1[e]);
    hi[4+e] = (short)h;
    lo[4+e] = (short)f2b(u1[e] - __uint_as_float((unsigned)h << 16));
  }
}
// async global->LDS, 16B per lane; lds dest must be wave-uniform base (HW adds lane*16)
__device__ __forceinline__ void gload16(const void* g, void* lds) {
  __builtin_amdgcn_global_load_lds(
      (const __attribute__((address_space(1))) unsigned int*)g,
      (__attribute__((address_space(3))) unsigned int*)lds, 16, 0, 0);
}

// ---------------- legacy f32 A1 kernel (fallback paths only)
__global__ __launch_bounds__(256) void kA1(const float* __restrict__ x, const float* __restrict__ Ws1,
                                           const float* __restrict__ bs1, float* __restrict__ A1)
{
  const int b0 = blockIdx.x * 64;
  const int c0 = blockIdx.y * 128;
  __shared__ float XS[32][68];
  __shared__ float WS[32][128];
  const int tid = threadIdx.x;
  const int ty = tid >> 4, tx = tid & 15;
  float acc[4][8];
  #pragma unroll
  for (int r = 0; r < 4; ++r)
    #pragma unroll
    for (int c = 0; c < 8; ++c) acc[r][c] = 0.f;

  for (int k0 = 0; k0 < Dd; k0 += 32) {
    #pragma unroll
    for (int it = 0; it < 2; ++it) {
      int i = tid + 256*it;
      int row = i >> 3, kq = i & 7;
      float4 v = *(const float4*)&x[(size_t)(b0+row)*Dd + k0 + 4*kq];
      XS[4*kq+0][row] = v.x; XS[4*kq+1][row] = v.y; XS[4*kq+2][row] = v.z; XS[4*kq+3][row] = v.w;
    }
    #pragma unroll
    for (int it = 0; it < 4; ++it) {
      int i = tid + 256*it;
      int k = i >> 5, cq = i & 31;
      *(float4*)&WS[k][4*cq] = *(const float4*)&Ws1[(size_t)(k0+k)*Hh + c0 + 4*cq];
    }
    __syncthreads();
    #pragma unroll
    for (int k = 0; k < 32; ++k) {
      const float4 xv = *(const float4*)&XS[k][ty*4];
      const float4 w0 = *(const float4*)&WS[k][tx*4];
      const float4 w1 = *(const float4*)&WS[k][tx*4+64];
      const float xr[4] = {xv.x, xv.y, xv.z, xv.w};
      const float wr[8] = {w0.x,w0.y,w0.z,w0.w,w1.x,w1.y,w1.z,w1.w};
      #pragma unroll
      for (int r = 0; r < 4; ++r)
        #pragma unroll
        for (int c = 0; c < 8; ++c)
          acc[r][c] = fmaf(xr[r], wr[c], acc[r][c]);
    }
    __syncthreads();
  }
  const float4 bv0 = *(const float4*)&bs1[c0 + tx*4];
  const float4 bv1 = *(const float4*)&bs1[c0 + tx*4 + 64];
  const float br[8] = {bv0.x,bv0.y,bv0.z,bv0.w,bv1.x,bv1.y,bv1.z,bv1.w};
  #pragma unroll
  for (int r = 0; r < 4; ++r) {
    int row = b0 + ty*4 + r;
    float o[8];
    #pragma unroll
    for (int c = 0; c < 8; ++c) o[c] = fmaxf(acc[r][c] + br[c], 0.f);
    float4 s0 = {o[0],o[1],o[2],o[3]};
    float4 s1 = {o[4],o[5],o[6],o[7]};
    *(float4*)&A1[(size_t)row*Hh + c0 + tx*4]      = s0;
    *(float4*)&A1[(size_t)row*Hh + c0 + tx*4 + 64] = s1;
  }
}

// ---------------- Ws1 transpose + hi/lo bf16 split: [1024][256] f32 -> 2x [256][1024] bf16
__global__ __launch_bounds__(256) void kTW(const float* __restrict__ in,
                                           unsigned short* __restrict__ hi,
                                           unsigned short* __restrict__ lo)
{
  const int i0 = blockIdx.x * 32, j0 = blockIdx.y * 32;
  __shared__ float T[32][33];
  const int t = threadIdx.x;
  {
    const int ii = t >> 3, jj = (t & 7) * 4;
    float4 v = *(const float4*)&in[(size_t)(i0+ii)*Hh + j0 + jj];
    T[ii][jj] = v.x; T[ii][jj+1] = v.y; T[ii][jj+2] = v.z; T[ii][jj+3] = v.w;
  }
  __syncthreads();
  {
    const int jo = t >> 3, io = (t & 7) * 4;
    ushort4 sh, sl;
    float v0 = T[io+0][jo], v1 = T[io+1][jo], v2 = T[io+2][jo], v3 = T[io+3][jo];
    unsigned short h;
    h = f2b(v0); sh.x = h; sl.x = f2b(v0 - __uint_as_float((unsigned)h << 16));
    h = f2b(v1); sh.y = h; sl.y = f2b(v1 - __uint_as_float((unsigned)h << 16));
    h = f2b(v2); sh.z = h; sl.z = f2b(v2 - __uint_as_float((unsigned)h << 16));
    h = f2b(v3); sh.w = h; sl.w = f2b(v3 - __uint_as_float((unsigned)h << 16));
    *(ushort4*)&hi[(size_t)(j0+jo)*Dd + i0 + io] = sh;
    *(ushort4*)&lo[(size_t)(j0+jo)*Dd + i0 + io] = sl;
  }
}

// ---------------- Ws2 transpose: [256][48] f32 -> [48][256] f32 (for kB3 staging)
__global__ __launch_bounds__(256) void kT2(const float* __restrict__ Ws2, float* __restrict__ Ws2T)
{
  const int j = blockIdx.x;            // 0..47
  const int k = threadIdx.x;           // 0..255
  Ws2T[(size_t)j * Hh + k] = Ws2[(size_t)k * 48 + j];
}

// ---------------- kA1s7: A1 = relu(x @ Ws1 + bs1), split-bf16 MFMA, COUNTED-VMCNT pipeline.
// kA1s3 geometry (32x128, split-once X->LDS bf16 planes: bit-identical validated chain).
// Double-buffered X(2x8KB)+W(2x32KB) = 80KB dynamic LDS. Per iteration:
//   A: ds_write X[k+1] -> Xbuf[nxt]
//   B: reg-load x[k+2] (clamped)
//   C: ds_read + 24 MFMA on chunk k from buf[cur]
//   D: s_waitcnt vmcnt(2) lgkmcnt(0)  (W[k+1] done; x[k+2] stays in flight) + raw s_barrier
//   E: issue 8 gload_lds for W[k+2] -> Wbuf[cur]   (fly through next full iteration)
// vmcnt never drains to 0 in the main loop (T4).
__global__ __launch_bounds__(256) void kA1s7(const float* __restrict__ x,
    const unsigned short* __restrict__ Whi, const unsigned short* __restrict__ Wlo,
    const float* __restrict__ bs1, float* __restrict__ A1)
{
  extern __shared__ __align__(16) char sm[];
  // Xbuf b @ b*8192 (Xh +0 4KB, Xl +4096) ; Wbuf b @ 16384 + b*32768 (Bh +0 16KB, Bl +16384)

  const int bid = blockIdx.x;
  const int b0 = (bid >> 1) * 32;
  const int cb = bid & 1;
  const int tid = threadIdx.x, l = tid & 63, w = tid >> 6;

  // X staging: thread -> (row = tid>>3, granule = tid&7); xor-swizzled slot
  const int xrow = tid >> 3, xga = tid & 7;
  const int xdst = xrow * 128 + ((xga ^ (xrow & 7)) * 16);
  const size_t xsrc = (size_t)(b0 + xrow) * Dd + xga * 8;

  // W staging via gload_lds with pre-swizzled source (wave-uniform LDS dest)
  const unsigned short *hsrc[4], *lsrc[4];
  const unsigned short* Hbase = Whi + (size_t)(cb * 128) * Dd;
  const unsigned short* Lbase = Wlo + (size_t)(cb * 128) * Dd;
  #pragma unroll
  for (int t = 0; t < 4; ++t) {
    const int col = (w * 4 + t) * 8 + (l >> 3);
    const int sa = (l & 7) ^ (col & 7);
    hsrc[t] = Hbase + (size_t)col * Dd + sa * 8;
    lsrc[t] = Lbase + (size_t)col * Dd + sa * 8;
  }

  f32x4 acc[2][2];
  #pragma unroll
  for (int a = 0; a < 2; ++a)
    #pragma unroll
    for (int b_ = 0; b_ < 2; ++b_)
      #pragma unroll
      for (int e = 0; e < 4; ++e) acc[a][b_][e] = 0.f;

  // ---- prologue: issue order per wave = [x0(2), W0(8), x1(2), W1(8)]
  f32x4 x0a = *(const f32x4*)&x[xsrc];
  f32x4 x0b = *(const f32x4*)&x[xsrc + 4];
  #pragma unroll
  for (int t = 0; t < 4; ++t) {
    gload16(hsrc[t], sm + 16384 + (w * 4 + t) * 1024);
    gload16(lsrc[t], sm + 16384 + 16384 + (w * 4 + t) * 1024);
  }
  f32x4 xa = *(const f32x4*)&x[xsrc + 64];
  f32x4 xb = *(const f32x4*)&x[xsrc + 68];
  #pragma unroll
  for (int t = 0; t < 4; ++t) {
    gload16(hsrc[t] + 64, sm + 16384 + 32768 + (w * 4 + t) * 1024);
    gload16(lsrc[t] + 64, sm + 16384 + 32768 + 16384 + (w * 4 + t) * 1024);
  }
  {
    s16x8 hi8, lo8;
    split8(x0a, x0b, hi8, lo8);          // compiler waits x0 (vmcnt<=18), W0.. stay in flight
    *(s16x8*)(sm + xdst) = hi8;
    *(s16x8*)(sm + 4096 + xdst) = lo8;
  }
  asm volatile("s_waitcnt vmcnt(10) lgkmcnt(0)" ::: "memory");  // W0 done; x1+W1 in flight
  __builtin_amdgcn_s_barrier();

  for (int kc = 0; kc < 15; ++kc) {
    const int cur = kc & 1, nxt = cur ^ 1;
    const char* Xb = sm + cur * 8192;
    const char* Bb = sm + 16384 + cur * 32768;

    // A: publish X chunk kc+1 (xregs loaded last iter; compiler waits them, W stays in flight)
    {
      s16x8 hi8, lo8;
      split8(xa, xb, hi8, lo8);
      *(s16x8*)(sm + nxt * 8192 + xdst) = hi8;
      *(s16x8*)(sm + nxt * 8192 + 4096 + xdst) = lo8;
    }
    // B: reg-load x chunk kc+2 (clamped dummy at tail keeps vmcnt accounting uniform)
    {
      const int kn = kc + 2 < 16 ? kc + 2 : 15;
      xa = *(const f32x4*)&x[xsrc + kn * 64];
      xb = *(const f32x4*)&x[xsrc + kn * 64 + 4];
    }
    // C: compute chunk kc from buf[cur]
    #pragma unroll
    for (int kk = 0; kk < 2; ++kk) {
      s16x8 ah[2], al[2], bh[2], bl[2];
      #pragma unroll
      for (int rf = 0; rf < 2; ++rf) {
        const int row = rf * 16 + (l & 15);
        const int g = (kk * 4 + (l >> 4)) ^ (row & 7);
        ah[rf] = *(const s16x8*)(Xb + row * 128 + g * 16);
        al[rf] = *(const s16x8*)(Xb + 4096 + row * 128 + g * 16);
      }
      #pragma unroll
      for (int cf = 0; cf < 2; ++cf) {
        const int col = w * 32 + cf * 16 + (l & 15);
        const int g = (kk * 4 + (l >> 4)) ^ (col & 7);
        bh[cf] = *(const s16x8*)(Bb + col * 128 + g * 16);
        bl[cf] = *(const s16x8*)(Bb + 16384 + col * 128 + g * 16);
      }
      #pragma unroll
      for (int rf = 0; rf < 2; ++rf)
        #pragma unroll
        for (int cf = 0; cf < 2; ++cf) {
          acc[rf][cf] = MFMA_BF16(ah[rf], bh[cf], acc[rf][cf]);
          acc[rf][cf] = MFMA_BF16(ah[rf], bl[cf], acc[rf][cf]);
          acc[rf][cf] = MFMA_BF16(al[rf], bh[cf], acc[rf][cf]);
        }
    }
    // D: counted drain (W[kc+1] retired, x[kc+2] in flight) + raw barrier
    asm volatile("s_waitcnt vmcnt(2) lgkmcnt(0)" ::: "memory");
    __builtin_amdgcn_s_barrier();
    // E: issue W chunk kc+2 into Wbuf[cur] (reads of cur finished before the barrier)
    {
      const int kn = kc + 2 < 16 ? kc + 2 : 15;
      char* Wd = sm + 16384 + cur * 32768;
      #pragma unroll
      for (int t = 0; t < 4; ++t) {
        gload16(hsrc[t] + kn * 64, Wd + (w * 4 + t) * 1024);
        gload16(lsrc[t] + kn * 64, Wd + 16384 + (w * 4 + t) * 1024);
      }
    }
  }

  // epilogue: chunk 15 from buf[1] (complete per D of kc=14)
  {
    const char* Xb = sm + 8192;
    const char* Bb = sm + 16384 + 32768;
    #pragma unroll
    for (int kk = 0; kk < 2; ++kk) {
      s16x8 ah[2], al[2], bh[2], bl[2];
      #pragma unroll
      for (int rf = 0; rf < 2; ++rf) {
        const int row = rf * 16 + (l & 15);
        const int g = (kk * 4 + (l >> 4)) ^ (row & 7);
        ah[rf] = *(const s16x8*)(Xb + row * 128 + g * 16);
        al[rf] = *(const s16x8*)(Xb + 4096 + row * 128 + g * 16);
      }
      #pragma unroll
      for (int cf = 0; cf < 2; ++cf) {
        const int col = w * 32 + cf * 16 + (l & 15);
        const int g = (kk * 4 + (l >> 4)) ^ (col & 7);
        bh[cf] = *(const s16x8*)(Bb + col * 128 + g * 16);
        bl[cf] = *(const s16x8*)(Bb + 16384 + col * 128 + g * 16);
      }
      #pragma unroll
      for (int rf = 0; rf < 2; ++rf)
        #pragma unroll
        for (int cf = 0; cf < 2; ++cf) {
          acc[rf][cf] = MFMA_BF16(ah[rf], bh[cf], acc[rf][cf]);
          acc[rf][cf] = MFMA_BF16(ah[rf], bl[cf], acc[rf][cf]);
          acc[rf][cf] = MFMA_BF16(al[rf], bh[cf], acc[rf][cf]);
        }
    }
  }

  // store: bias + relu
  #pragma unroll
  for (int rf = 0; rf < 2; ++rf)
    #pragma unroll
    for (int cf = 0; cf < 2; ++cf)
      #pragma unroll
      for (int rg = 0; rg < 4; ++rg) {
        const int row = b0 + rf * 16 + (l >> 4) * 4 + rg;
        const int col = cb * 128 + w * 32 + cf * 16 + (l & 15);
        A1[(size_t)row * Hh + col] = fmaxf(acc[rf][cf][rg] + bs1[col], 0.f);
      }
}

// ---------------- ctrl = A1 @ Ws2 + bs2 (fallback path only)
__global__ __launch_bounds__(256) void kA2(const float* __restrict__ Ws2, const float* __restrict__ bs2,
                                           float* out)
{
  const int b0 = blockIdx.x * 64;
  __shared__ float XS[32][68];
  __shared__ float WC[32][48];
  const int tid = threadIdx.x;
  const int rg = tid >> 4, jg = tid & 15;
  float acc[4][3];
  #pragma unroll
  for (int r = 0; r < 4; ++r) { acc[r][0]=0.f; acc[r][1]=0.f; acc[r][2]=0.f; }
  const float* A1 = out;
  for (int kc = 0; kc < 8; ++kc) {
    const int k0 = kc*32;
    #pragma unroll
    for (int it = 0; it < 2; ++it) {
      int i = tid + 256*it;
      int row = i >> 3, kq = i & 7;
      float4 v = *(const float4*)&A1[(size_t)(b0+row)*Hh + k0 + 4*kq];
      XS[4*kq+0][row]=v.x; XS[4*kq+1][row]=v.y; XS[4*kq+2][row]=v.z; XS[4*kq+3][row]=v.w;
    }
    #pragma unroll
    for (int it = 0; it < 2; ++it) {
      int i = tid + 256*it;
      if (i < 384) {
        int k = i / 12, jq = i % 12;
        *(float4*)&WC[k][4*jq] = *(const float4*)&Ws2[(size_t)(k0+k)*48 + 4*jq];
      }
    }
    __syncthreads();
    #pragma unroll
    for (int k = 0; k < 32; ++k) {
      const float4 av = *(const float4*)&XS[k][rg*4];
      const float ar[4] = {av.x,av.y,av.z,av.w};
      const float w0 = WC[k][jg], w1 = WC[k][jg+16], w2 = WC[k][jg+32];
      #pragma unroll
      for (int r = 0; r < 4; ++r) {
        acc[r][0] = fmaf(ar[r], w0, acc[r][0]);
        acc[r][1] = fmaf(ar[r], w1, acc[r][1]);
        acc[r][2] = fmaf(ar[r], w2, acc[r][2]);
      }
    }
    __syncthreads();
  }
  const float c0b = bs2[jg], c1b = bs2[jg+16], c2b = bs2[jg+32];
  #pragma unroll
  for (int r = 0; r < 4; ++r) {
    size_t row = (size_t)b0 + rg*4 + r;
    out[O1 + row*NBk + jg] = acc[r][0] + c0b;
    out[O4 + row*NBk + jg] = acc[r][1] + c1b;
    out[O5 + row*NBk + jg] = acc[r][2] + c2b;
  }
}

// ---------------- kB2: element-parallel gumbel/softmax/argmax/z (fallback; reads ctrl from out)
__global__ __launch_bounds__(256) void kB2(const float* __restrict__ u, const float* __restrict__ eps,
                                           float* out, int* __restrict__ idxw, float* __restrict__ zsel,
                                           int* __restrict__ counts)
{
  const int e = blockIdx.x * 256 + threadIdx.x;
  const int b = e >> 4, j = e & 15;
  const float yl = out[O1 + e];
  const float zm = out[O4 + e];
  const float zv = out[O5 + e];
  const float s  = yl - logf(-logf(u[e]));
  const float z  = zm + expf(0.5f * zv) * eps[e];

  float bv = s; int bj = j;
  #pragma unroll
  for (int m = 8; m >= 1; m >>= 1) {
    const float ov = __shfl_xor(bv, m, 16);
    const int   oj = __shfl_xor(bj, m, 16);
    if (ov > bv || (ov == bv && oj < bj)) { bv = ov; bj = oj; }
  }
  const float ex = expf(s - bv);
  float sum = ex;
  #pragma unroll
  for (int m = 8; m >= 1; m >>= 1) sum += __shfl_xor(sum, m, 16);
  const float inv = 1.f / sum;

  out[O3 + e] = ex * inv;
  out[O6 + e] = z;
  if (j == bj) {
    out[O2 + b] = (float)bj;
    idxw[b] = bj;
    zsel[b] = z;
    atomicAdd(&counts[bj], 1);
  }
}

// ---------------- kB3: FUSED ctrl GEMM + gumbel/softmax/argmax/z, LDS-staged
__global__ __launch_bounds__(256) void kB3(const float* __restrict__ A1, const float* __restrict__ Ws2T,
                                           const float* __restrict__ bs2,
                                           const float* __restrict__ u, const float* __restrict__ eps,
                                           float* out, int* __restrict__ idxw, float* __restrict__ zsel)
{
  __shared__ float AS[16][258];
  __shared__ float WS[48][258];
  const int tid = threadIdx.x;
  const int brow0 = blockIdx.x * 16;

  #pragma unroll
  for (int it = 0; it < 4; ++it) {
    const int i = tid + 256 * it;
    const int row = i >> 6, kq = i & 63;
    const f32x4 v = *(const f32x4*)&A1[(size_t)(brow0 + row) * Hh + kq * 4];
    *(f32x4*)&AS[row][kq * 4] = v;
  }
  #pragma unroll
  for (int it = 0; it < 12; ++it) {
    const int i = tid + 256 * it;
    const int row = i >> 6, kq = i & 63;
    const f32x4 v = *(const f32x4*)&Ws2T[(size_t)row * Hh + kq * 4];
    *(f32x4*)&WS[row][kq * 4] = v;
  }
  __syncthreads();

  const int e = blockIdx.x * 256 + tid;
  const int b = e >> 4, j = tid & 15;
  const int rl = tid >> 4;

  float c0 = 0.f, c1 = 0.f, c2 = 0.f;
  #pragma unroll 4
  for (int k = 0; k < Hh; k += 4) {
    const f32x4 av = *(const f32x4*)&AS[rl][k];
    const f32x4 wa = *(const f32x4*)&WS[j][k];
    const f32x4 wb = *(const f32x4*)&WS[j + 16][k];
    const f32x4 wc = *(const f32x4*)&WS[j + 32][k];
    #pragma unroll
    for (int kk = 0; kk < 4; ++kk) {   // ascending k: bit-identical chain
      c0 = fmaf(av[kk], wa[kk], c0);
      c1 = fmaf(av[kk], wb[kk], c1);
      c2 = fmaf(av[kk], wc[kk], c2);
    }
  }
  const float yl = c0 + bs2[j];
  const float zm = c1 + bs2[j + 16];
  const float zv = c2 + bs2[j + 32];

  const float s = yl - logf(-logf(u[e]));
  const float z = zm + expf(0.5f * zv) * eps[e];

  float bv = s; int bj = j;
  #pragma unroll
  for (int m = 8; m >= 1; m >>= 1) {
    const float ov = __shfl_xor(bv, m, 16);
    const int   oj = __shfl_xor(bj, m, 16);
    if (ov > bv || (ov == bv && oj < bj)) { bv = ov; bj = oj; }
  }
  const float ex = expf(s - bv);
  float sum = ex;
  #pragma unroll
  for (int m = 8; m >= 1; m >>= 1) sum += __shfl_xor(sum, m, 16);
  const float inv = 1.f / sum;

  out[O1 + e] = yl;
  out[O4 + e] = zm;
  out[O5 + e] = zv;
  out[O3 + e] = ex * inv;
  out[O6 + e] = z;
  if (j == bj) {
    out[O2 + b] = (float)bj;
    idxw[b] = bj;
    zsel[b] = z;
  }
}

// ---------------- kH: expert histogram, block-aggregated
__global__ __launch_bounds__(256) void kH(const int* __restrict__ idxw, int* __restrict__ counts)
{
  __shared__ int lh[NBk];
  const int tid = threadIdx.x;
  if (tid < NBk) lh[tid] = 0;
  __syncthreads();
  atomicAdd(&lh[idxw[blockIdx.x * 256 + tid]], 1);
  __syncthreads();
  if (tid < NBk && lh[tid]) atomicAdd(&counts[tid], lh[tid]);
}

// ---------------- prefix sums over 16 experts
__global__ void kP(const int* __restrict__ counts, int* __restrict__ offs, int* __restrict__ cursor,
                   int* __restrict__ bpre, int* __restrict__ tp1, int* __restrict__ tp2,
                   int* __restrict__ seg)
{
  if (threadIdx.x == 0 && blockIdx.x == 0) {
    int a = 0, bb = 0, t1 = 0, t2 = 0, sg = 0;
    for (int n = 0; n < NBk; ++n) {
      offs[n] = a; cursor[n] = a; bpre[n] = bb; tp1[n] = t1; tp2[n] = t2; seg[n] = sg;
      const int c = counts[n];
      a  += c;
      bb += (c + 31) >> 5;
      t1 += (c + 63) >> 6;
      t2 += (c + 127) >> 7;
      sg += ((c + 127) >> 7) * 128;
    }
    offs[NBk] = a; bpre[NBk] = bb; tp1[NBk] = t1; tp2[NBk] = t2; seg[NBk] = sg;
  }
}

// ---------------- kS: per-row scatter (fallback)
__global__ __launch_bounds__(256) void kS(const int* __restrict__ idxw, int* __restrict__ cursor,
                                          int* __restrict__ rowlist)
{
  const int b = blockIdx.x * 256 + threadIdx.x;
  const int n = idxw[b];
  const int pos = atomicAdd(&cursor[n], 1);
  rowlist[pos] = b;
}

// ---------------- kS2: block-aggregated scatter
__global__ __launch_bounds__(256) void kS2(const int* __restrict__ idxw, int* __restrict__ cursor,
                                           int* __restrict__ rowlist)
{
  __shared__ int lh[NBk];
  __shared__ int gb[NBk];
  const int tid = threadIdx.x;
  const int b = blockIdx.x * 256 + tid;
  const int n = idxw[b];
  if (tid < NBk) lh[tid] = 0;
  __syncthreads();
  const int rank = atomicAdd(&lh[n], 1);
  __syncthreads();
  if (tid < NBk) gb[tid] = lh[tid] ? atomicAdd(&cursor[tid], lh[tid]) : 0;
  __syncthreads();
  rowlist[gb[n] + rank] = b;
}

// ---------------- transpose + convert: in [n][R][C] f32 -> out [n][C][R] bf16
__global__ __launch_bounds__(256) void kT(const float* __restrict__ in, unsigned short* __restrict__ out,
                                          int R, int C)
{
  const int n = blockIdx.z;
  in  += (size_t)n * R * C;
  out += (size_t)n * R * C;
  const int i0 = blockIdx.x * 32, j0 = blockIdx.y * 32;
  __shared__ float T[32][33];
  const int t = threadIdx.x;
  {
    const int ii = t >> 3, jj = (t & 7) * 4;
    float4 v = *(const float4*)&in[(size_t)(i0+ii)*C + j0 + jj];
    T[ii][jj] = v.x; T[ii][jj+1] = v.y; T[ii][jj+2] = v.z; T[ii][jj+3] = v.w;
  }
  __syncthreads();
  {
    const int jo = t >> 3, io = (t & 7) * 4;
    ushort4 st;
    st.x = f2b(T[io+0][jo]);
    st.y = f2b(T[io+1][jo]);
    st.z = f2b(T[io+2][jo]);
    st.w = f2b(T[io+3][jo]);
    *(ushort4*)&out[(size_t)(j0+jo)*R + i0 + io] = st;
  }
}

// ================= kG1: h = relu(x @ W1[n] + b1)*z  (gload_lds + cvt8; proven form)
__global__ __launch_bounds__(256) void kG1(const float* __restrict__ x,
    const unsigned short* __restrict__ W1T, const float* __restrict__ b1,
    const int* __restrict__ rowlist, const float* __restrict__ zsel,
    const int* __restrict__ offs, const int* __restrict__ tp1, const int* __restrict__ seg,
    unsigned short* __restrict__ hbuf)
{
  __shared__ __align__(16) float Xs[64*64];
  __shared__ __align__(16) unsigned short Wsh[128*64];
  __shared__ int rows_s[64];
  __shared__ float zrs[64];

  const int bid = blockIdx.x;
  const int tile = bid >> 1, cb = bid & 1;
  if (tile >= tp1[NBk]) return;
  int n = 0;
  while (tile >= tp1[n+1]) ++n;
  const int tt = tile - tp1[n];
  const int base = offs[n], cnt = offs[n+1] - base;
  const int r0 = tt * 64;
  const int tid = threadIdx.x, l = tid & 63, w = tid >> 6;
  const int wr = w >> 1, wc = w & 1;

  if (tid < 64) {
    int r = r0 + tid;
    int g = rowlist[base + (r < cnt ? r : cnt - 1)];
    rows_s[tid] = g;
    zrs[tid] = zsel[g];
  }
  __syncthreads();

  size_t xsrc[4];
  const unsigned short* wsrc[4];
  const unsigned short* Wbase = W1T + (size_t)n * (Hh * Dd) + (size_t)(cb * 128) * Dd;
  #pragma unroll
  for (int t = 0; t < 4; ++t) {
    {
      int row = (w * 4 + t) * 4 + (l >> 4);
      int ga = (l & 15) ^ (row & 7);
      xsrc[t] = (size_t)rows_s[row] * Dd + ga * 4;
    }
    {
      int row = (w * 4 + t) * 8 + (l >> 3);
      int sa = (l & 7) ^ (row & 7);
      wsrc[t] = Wbase + (size_t)row * Dd + sa * 8;
    }
  }

  f32x4 acc[2][4];
  #pragma unroll
  for (int a = 0; a < 2; ++a)
    #pragma unroll
    for (int b_ = 0; b_ < 4; ++b_)
      #pragma unroll
      for (int e = 0; e < 4; ++e) acc[a][b_][e] = 0.f;

  for (int kc = 0; kc < 16; ++kc) {
    #pragma unroll
    for (int t = 0; t < 4; ++t) {
      gload16(&x[xsrc[t] + kc * 64], (char*)Xs + (w * 4 + t) * 1024);
      gload16(wsrc[t] + kc * 64, (char*)Wsh + (w * 4 + t) * 1024);
    }
    __syncthreads();

    #pragma unroll
    for (int kk = 0; kk < 2; ++kk) {
      s16x8 af[2], bf[4];
      #pragma unroll
      for (int rf = 0; rf < 2; ++rf) {
        const int row = wr * 32 + rf * 16 + (l & 15);
        const int gl = 8 * kk + 2 * (l >> 4);
        const int g0 = gl ^ (row & 7), g1 = (gl + 1) ^ (row & 7);
        f32x4 u0 = *(const f32x4*)((const char*)Xs + row * 256 + g0 * 16);
        f32x4 u1 = *(const f32x4*)((const char*)Xs + row * 256 + g1 * 16);
        af[rf] = cvt8(u0, u1);
      }
      #pragma unroll
      for (int cf = 0; cf < 4; ++cf) {
        const int col = wc * 64 + cf * 16 + (l & 15);
        const int s8 = (4 * kk + (l >> 4)) ^ (col & 7);
        bf[cf] = *(const s16x8*)((const char*)Wsh + col * 128 + s8 * 16);
      }
      #pragma unroll
      for (int rf = 0; rf < 2; ++rf)
        #pragma unroll
        for (int cf = 0; cf < 4; ++cf)
          acc[rf][cf] = MFMA_BF16(af[rf], bf[cf], acc[rf][cf]);
    }
    __syncthreads();
  }

  const size_t hrow0 = (size_t)seg[n] + r0;
  #pragma unroll
  for (int rf = 0; rf < 2; ++rf)
    #pragma unroll
    for (int cf = 0; cf < 4; ++cf)
      #pragma unroll
      for (int rg = 0; rg < 4; ++rg) {
        const int rloc = wr * 32 + rf * 16 + (l >> 4) * 4 + rg;
        const int col = cb * 128 + wc * 64 + cf * 16 + (l & 15);
        const float hv = fmaxf(acc[rf][cf][rg] + b1[n * Hh + col], 0.f) * zrs[rloc];
        hbuf[(hrow0 + rloc) * Hh + col] = f2b(hv);
      }
}

// ================= kG2: out = h @ W2[n] + b2 + x  (128-row x 128-col tiles, 8 col-blocks)
__global__ __launch_bounds__(256) void kG2(const float* __restrict__ x,
    const unsigned short* __restrict__ W2T, const float* __restrict__ b2,
    const unsigned short* __restrict__ hbuf, const int* __restrict__ rowlist,
    const int* __restrict__ offs, const int* __restrict__ tp2, const int* __restrict__ seg,
    float* __restrict__ out)
{
  __shared__ __align__(16) unsigned short As[128*64];
  __shared__ __align__(16) unsigned short Bs[128*64];
  __shared__ int rows_s[128];

  const int bid = blockIdx.x;
  const int tile = bid >> 3, cb = bid & 7;
  if (tile >= tp2[NBk]) return;
  int n = 0;
  while (tile >= tp2[n+1]) ++n;
  const int tt = tile - tp2[n];
  const int base = offs[n], cnt = offs[n+1] - base;
  const int r0 = tt * 128;
  const int tid = threadIdx.x, l = tid & 63, w = tid >> 6;
  const int wr = w >> 1, wc = w & 1;

  if (tid < 128) {
    int r = r0 + tid;
    rows_s[tid] = rowlist[base + (r < cnt ? r : cnt - 1)];
  }
  __syncthreads();

  const unsigned short* Abase = hbuf + (size_t)(seg[n] + r0) * Hh;
  const unsigned short* Bbase = W2T + (size_t)n * (Hh * Dd) + (size_t)(cb * 128) * Hh;

  const unsigned short* asrc[4];
  const unsigned short* bsrc[4];
  #pragma unroll
  for (int t = 0; t < 4; ++t) {
    const int row = (w * 4 + t) * 8 + (l >> 3);
    const int sa = (l & 7) ^ (row & 7);
    asrc[t] = Abase + (size_t)row * Hh + sa * 8;
    bsrc[t] = Bbase + (size_t)row * Hh + sa * 8;
  }

  f32x4 acc[4][4];
  #pragma unroll
  for (int a = 0; a < 4; ++a)
    #pragma unroll
    for (int b_ = 0; b_ < 4; ++b_)
      #pragma unroll
      for (int e = 0; e < 4; ++e) acc[a][b_][e] = 0.f;

  for (int kc = 0; kc < 4; ++kc) {
    #pragma unroll
    for (int t = 0; t < 4; ++t) {
      gload16(asrc[t] + kc * 64, (char*)As + (w * 4 + t) * 1024);
      gload16(bsrc[t] + kc * 64, (char*)Bs + (w * 4 + t) * 1024);
    }
    __syncthreads();

    #pragma unroll
    for (int kk = 0; kk < 2; ++kk) {
      s16x8 af[4], bf[4];
      #pragma unroll
      for (int rf = 0; rf < 4; ++rf) {
        const int row = wr * 64 + rf * 16 + (l & 15);
        const int s8 = (4 * kk + (l >> 4)) ^ (row & 7);
        af[rf] = *(const s16x8*)((const char*)As + row * 128 + s8 * 16);
      }
      #pragma unroll
      for (int cf = 0; cf < 4; ++cf) {
        const int col = wc * 64 + cf * 16 + (l & 15);
        const int s8 = (4 * kk + (l >> 4)) ^ (col & 7);
        bf[cf] = *(const s16x8*)((const char*)Bs + col * 128 + s8 * 16);
      }
      #pragma unroll
      for (int rf = 0; rf < 4; ++rf)
        #pragma unroll
        for (int cf = 0; cf < 4; ++cf)
          acc[rf][cf] = MFMA_BF16(af[rf], bf[cf], acc[rf][cf]);
    }
    __syncthreads();
  }

  #pragma unroll
  for (int rf = 0; rf < 4; ++rf)
    #pragma unroll
    for (int rg = 0; rg < 4; ++rg) {
      const int rloc = wr * 64 + rf * 16 + (l >> 4) * 4 + rg;
      if (r0 + rloc < cnt) {
        const int g = rows_s[rloc];
        #pragma unroll
        for (int cf = 0; cf < 4; ++cf) {
          const int col = cb * 128 + wc * 64 + cf * 16 + (l & 15);
          out[(size_t)g * Dd + col] = acc[rf][cf][rg] + b2[n * Dd + col] + x[(size_t)g * Dd + col];
        }
      }
    }
}

extern "C" void kernel_launch(void* const* d_in, const int* in_sizes, int n_in,
                              void* d_out, int out_size, void* d_ws, size_t ws_size,
                              hipStream_t stream) {
  const float* x   = (const float*)d_in[0];
  const float* Ws1 = (const float*)d_in[1];
  const float* bs1 = (const float*)d_in[2];
  const float* Ws2 = (const float*)d_in[3];
  const float* bs2 = (const float*)d_in[4];
  const float* W1  = (const float*)d_in[5];
  const float* b1  = (const float*)d_in[6];
  const float* W2  = (const float*)d_in[7];
  const float* b2  = (const float*)d_in[8];
  const float* u   = (const float*)d_in[9];
  const float* eps = (const float*)d_in[10];
  float* out = (float*)d_out;

  char* ws = (char*)d_ws;
  int*   counts  = (int*)(ws + 0);
  int*   cursor  = (int*)(ws + 64);
  int*   bpre    = (int*)(ws + 128);
  int*   offs    = (int*)(ws + 256);
  int*   tp1     = (int*)(ws + 384);
  int*   tp2     = (int*)(ws + 512);
  int*   seg     = (int*)(ws + 640);
  int*   idxw    = (int*)(ws + 4096);
  float* zsel    = (float*)(ws + 4096 + 65536);
  int*   rowlist = (int*)(ws + 4096 + 131072);
  float* Ws2T    = (float*)(ws + 786432);                             // [48][256] f32 = 48KB
  unsigned short* W1T  = (unsigned short*)(ws + ((size_t)1 << 20));   // [16][256][1024] bf16 = 8MB
  unsigned short* W2T  = (unsigned short*)(ws + ((size_t)9 << 20));   // [16][1024][256] bf16 = 8MB
  unsigned short* hbuf = (unsigned short*)(ws + ((size_t)17 << 20));  // [<=18432][256] bf16 = 9.44MB
  unsigned short* Whi  = (unsigned short*)(ws + ((size_t)27 << 20));  // [256][1024] bf16 = 512KB
  unsigned short* Wlo  = (unsigned short*)(ws + ((size_t)27 << 20) + (512<<10)); // 512KB

  const bool f2 = ws_size >= ((size_t)28 << 20);
  const bool f1 = ws_size >= ((size_t)18 << 20);

  hipMemsetAsync(d_ws, 0, 4096, stream);
  if (f1 || f2) {
    kT<<<dim3(32, 8, 16), 256, 0, stream>>>(W1, W1T, Dd, Hh);   // -> [n][h][d]
    kT<<<dim3(8, 32, 16), 256, 0, stream>>>(W2, W2T, Hh, Dd);   // -> [n][d][h]
  }
  if (f2) {
    kTW<<<dim3(32, 8), 256, 0, stream>>>(Ws1, Whi, Wlo);        // Ws1^T hi/lo bf16
    kT2<<<dim3(48), 256, 0, stream>>>(Ws2, Ws2T);               // Ws2^T f32
    kA1s7<<<dim3(1024), 256, 81920, stream>>>(x, Whi, Wlo, bs1, out); // A1, counted-vmcnt
    kB3<<<dim3(Bn/16), 256, 0, stream>>>(out, Ws2T, bs2, u, eps, out, idxw, zsel);
    kH <<<dim3(Bn/256), 256, 0, stream>>>(idxw, counts);        // block-aggregated counts
  } else {
    kA1<<<dim3(Bn/64, 2), 256, 0, stream>>>(x, Ws1, bs1, out);
    kA2<<<dim3(Bn/64), 256, 0, stream>>>(Ws2, bs2, out);
    kB2<<<dim3(Bn*NBk/256), 256, 0, stream>>>(u, eps, out, idxw, zsel, counts);
  }
  kP <<<dim3(1), 64, 0, stream>>>(counts, offs, cursor, bpre, tp1, tp2, seg);
  if (f2) {
    kS2<<<dim3(Bn/256), 256, 0, stream>>>(idxw, cursor, rowlist); // block-aggregated scatter
    kG1<<<dim3(544), 256, 0, stream>>>(x, W1T, b1, rowlist, zsel, offs, tp1, seg, hbuf);
    kG2<<<dim3(1152), 256, 0, stream>>>(x, W2T, b2, hbuf, rowlist, offs, tp2, seg, out);
  } else {
    kS<<<dim3(Bn/256), 256, 0, stream>>>(idxw, cursor, rowlist);
  }
}

// Round 16
// 159.505 us; speedup vs baseline: 1.0927x; 1.0927x over previous
//
#include <hip/hip_runtime.h>
#include <hip/hip_bf16.h>
#include <stdint.h>

#define Bn 16384
#define Dd 1024
#define Hh 256
#define NBk 16

// d_out layout (all float32): x+out | y_logits | y_idx | y | z_mean | z_logvar | z
#define O1 ((size_t)Bn*Dd)
#define O2 (O1 + (size_t)Bn*NBk)
#define O3 (O2 + (size_t)Bn)
#define O4 (O3 + (size_t)Bn*NBk)
#define O5 (O4 + (size_t)Bn*NBk)
#define O6 (O5 + (size_t)Bn*NBk)

typedef __attribute__((ext_vector_type(8))) short s16x8;
typedef __attribute__((ext_vector_type(4))) float f32x4;

#define MFMA_BF16(a,b,c) __builtin_amdgcn_mfma_f32_16x16x32_bf16((a),(b),(c),0,0,0)

__device__ __forceinline__ float blo(unsigned v){ return __uint_as_float(v << 16); }
__device__ __forceinline__ float bhi(unsigned v){ return __uint_as_float(v & 0xFFFF0000u); }
__device__ __forceinline__ unsigned short f2b(float f){   // f32 -> bf16 RNE
  unsigned u = __float_as_uint(f);
  return (unsigned short)((u + 0x7FFFu + ((u >> 16) & 1u)) >> 16);
}
__device__ __forceinline__ s16x8 cvt8(const f32x4 u0, const f32x4 u1) {
  s16x8 v;
  v[0]=(short)f2b(u0[0]); v[1]=(short)f2b(u0[1]); v[2]=(short)f2b(u0[2]); v[3]=(short)f2b(u0[3]);
  v[4]=(short)f2b(u1[0]); v[5]=(short)f2b(u1[1]); v[6]=(short)f2b(u1[2]); v[7]=(short)f2b(u1[3]);
  return v;
}
// split 8 f32 into bf16 hi + bf16 lo (x ~= hi + lo to ~2^-18 rel)
__device__ __forceinline__ void split8(const f32x4 u0, const f32x4 u1, s16x8& hi, s16x8& lo) {
  #pragma unroll
  for (int e = 0; e < 4; ++e) {
    const unsigned short h = f2b(u0[e]);
    hi[e] = (short)h;
    lo[e] = (short)f2b(u0[e] - __uint_as_float((unsigned)h << 16));
  }
  #pragma unroll
  for (int e = 0; e < 4; ++e) {
    const unsigned short h = f2b(u1[e]);
    hi[4+e] = (short)h;
    lo[4+e] = (short)f2b(u1[e] - __uint_as_float((unsigned)h << 16));
  }
}
// async global->LDS, 16B per lane; lds dest must be wave-uniform base (HW adds lane*16)
__device__ __forceinline__ void gload16(const void* g, void* lds) {
  __builtin_amdgcn_global_load_lds(
      (const __attribute__((address_space(1))) unsigned int*)g,
      (__attribute__((address_space(3))) unsigned int*)lds, 16, 0, 0);
}

// ---------------- legacy f32 A1 kernel (fallback paths only)
__global__ __launch_bounds__(256) void kA1(const float* __restrict__ x, const float* __restrict__ Ws1,
                                           const float* __restrict__ bs1, float* __restrict__ A1)
{
  const int b0 = blockIdx.x * 64;
  const int c0 = blockIdx.y * 128;
  __shared__ float XS[32][68];
  __shared__ float WS[32][128];
  const int tid = threadIdx.x;
  const int ty = tid >> 4, tx = tid & 15;
  float acc[4][8];
  #pragma unroll
  for (int r = 0; r < 4; ++r)
    #pragma unroll
    for (int c = 0; c < 8; ++c) acc[r][c] = 0.f;

  for (int k0 = 0; k0 < Dd; k0 += 32) {
    #pragma unroll
    for (int it = 0; it < 2; ++it) {
      int i = tid + 256*it;
      int row = i >> 3, kq = i & 7;
      float4 v = *(const float4*)&x[(size_t)(b0+row)*Dd + k0 + 4*kq];
      XS[4*kq+0][row] = v.x; XS[4*kq+1][row] = v.y; XS[4*kq+2][row] = v.z; XS[4*kq+3][row] = v.w;
    }
    #pragma unroll
    for (int it = 0; it < 4; ++it) {
      int i = tid + 256*it;
      int k = i >> 5, cq = i & 31;
      *(float4*)&WS[k][4*cq] = *(const float4*)&Ws1[(size_t)(k0+k)*Hh + c0 + 4*cq];
    }
    __syncthreads();
    #pragma unroll
    for (int k = 0; k < 32; ++k) {
      const float4 xv = *(const float4*)&XS[k][ty*4];
      const float4 w0 = *(const float4*)&WS[k][tx*4];
      const float4 w1 = *(const float4*)&WS[k][tx*4+64];
      const float xr[4] = {xv.x, xv.y, xv.z, xv.w};
      const float wr[8] = {w0.x,w0.y,w0.z,w0.w,w1.x,w1.y,w1.z,w1.w};
      #pragma unroll
      for (int r = 0; r < 4; ++r)
        #pragma unroll
        for (int c = 0; c < 8; ++c)
          acc[r][c] = fmaf(xr[r], wr[c], acc[r][c]);
    }
    __syncthreads();
  }
  const float4 bv0 = *(const float4*)&bs1[c0 + tx*4];
  const float4 bv1 = *(const float4*)&bs1[c0 + tx*4 + 64];
  const float br[8] = {bv0.x,bv0.y,bv0.z,bv0.w,bv1.x,bv1.y,bv1.z,bv1.w};
  #pragma unroll
  for (int r = 0; r < 4; ++r) {
    int row = b0 + ty*4 + r;
    float o[8];
    #pragma unroll
    for (int c = 0; c < 8; ++c) o[c] = fmaxf(acc[r][c] + br[c], 0.f);
    float4 s0 = {o[0],o[1],o[2],o[3]};
    float4 s1 = {o[4],o[5],o[6],o[7]};
    *(float4*)&A1[(size_t)row*Hh + c0 + tx*4]      = s0;
    *(float4*)&A1[(size_t)row*Hh + c0 + tx*4 + 64] = s1;
  }
}

// ---------------- Ws1 transpose + hi/lo bf16 split: [1024][256] f32 -> 2x [256][1024] bf16
__global__ __launch_bounds__(256) void kTW(const float* __restrict__ in,
                                           unsigned short* __restrict__ hi,
                                           unsigned short* __restrict__ lo)
{
  const int i0 = blockIdx.x * 32, j0 = blockIdx.y * 32;
  __shared__ float T[32][33];
  const int t = threadIdx.x;
  {
    const int ii = t >> 3, jj = (t & 7) * 4;
    float4 v = *(const float4*)&in[(size_t)(i0+ii)*Hh + j0 + jj];
    T[ii][jj] = v.x; T[ii][jj+1] = v.y; T[ii][jj+2] = v.z; T[ii][jj+3] = v.w;
  }
  __syncthreads();
  {
    const int jo = t >> 3, io = (t & 7) * 4;
    ushort4 sh, sl;
    float v0 = T[io+0][jo], v1 = T[io+1][jo], v2 = T[io+2][jo], v3 = T[io+3][jo];
    unsigned short h;
    h = f2b(v0); sh.x = h; sl.x = f2b(v0 - __uint_as_float((unsigned)h << 16));
    h = f2b(v1); sh.y = h; sl.y = f2b(v1 - __uint_as_float((unsigned)h << 16));
    h = f2b(v2); sh.z = h; sl.z = f2b(v2 - __uint_as_float((unsigned)h << 16));
    h = f2b(v3); sh.w = h; sl.w = f2b(v3 - __uint_as_float((unsigned)h << 16));
    *(ushort4*)&hi[(size_t)(j0+jo)*Dd + i0 + io] = sh;
    *(ushort4*)&lo[(size_t)(j0+jo)*Dd + i0 + io] = sl;
  }
}

// ---------------- Ws2 transpose: [256][48] f32 -> [48][256] f32 (for kB3 staging)
__global__ __launch_bounds__(256) void kT2(const float* __restrict__ Ws2, float* __restrict__ Ws2T)
{
  const int j = blockIdx.x;            // 0..47
  const int k = threadIdx.x;           // 0..255
  Ws2T[(size_t)j * Hh + k] = Ws2[(size_t)k * 48 + j];
}

// ---------------- A1 = relu(x @ Ws1 + bs1) via split-bf16 MFMA (hi*hi + hi*lo + lo*hi)
// ROUND-4 PROVEN FORM: gload_lds staging (zero staging VGPRs), 2-barrier loop, 48KB LDS.
__global__ __launch_bounds__(256) void kA1s(const float* __restrict__ x,
    const unsigned short* __restrict__ Whi, const unsigned short* __restrict__ Wlo,
    const float* __restrict__ bs1, float* __restrict__ A1)
{
  __shared__ __align__(16) float Xs[64*64];             // 16 KB f32 [64 rows][16 granules]
  __shared__ __align__(16) unsigned short Bh[128*64];   // 16 KB bf16 [128 cols][8 granules]
  __shared__ __align__(16) unsigned short Bl[128*64];   // 16 KB

  const int bid = blockIdx.x;
  const int b0 = (bid >> 1) * 64;
  const int cb = bid & 1;
  const int tid = threadIdx.x, l = tid & 63, w = tid >> 6;
  const int wr = w >> 1, wc = w & 1;

  // staging source addresses (XOR-swizzled so linear LDS dest + swz read match)
  size_t xsrc[4];
  const unsigned short *hsrc[4], *lsrc[4];
  const unsigned short* Hbase = Whi + (size_t)(cb * 128) * Dd;
  const unsigned short* Lbase = Wlo + (size_t)(cb * 128) * Dd;
  #pragma unroll
  for (int t = 0; t < 4; ++t) {
    {  // X: row stride 256B = 16 granules
      int row = (w * 4 + t) * 4 + (l >> 4);
      int ga = (l & 15) ^ (row & 7);
      xsrc[t] = (size_t)(b0 + row) * Dd + ga * 4;
    }
    {  // W planes: row stride 128B = 8 granules
      int row = (w * 4 + t) * 8 + (l >> 3);
      int sa = (l & 7) ^ (row & 7);
      hsrc[t] = Hbase + (size_t)row * Dd + sa * 8;
      lsrc[t] = Lbase + (size_t)row * Dd + sa * 8;
    }
  }

  f32x4 acc[2][4];
  #pragma unroll
  for (int a = 0; a < 2; ++a)
    #pragma unroll
    for (int b_ = 0; b_ < 4; ++b_)
      #pragma unroll
      for (int e = 0; e < 4; ++e) acc[a][b_][e] = 0.f;

  for (int kc = 0; kc < 16; ++kc) {
    #pragma unroll
    for (int t = 0; t < 4; ++t) {
      gload16(&x[xsrc[t] + kc * 64], (char*)Xs + (w * 4 + t) * 1024);
      gload16(hsrc[t] + kc * 64, (char*)Bh + (w * 4 + t) * 1024);
      gload16(lsrc[t] + kc * 64, (char*)Bl + (w * 4 + t) * 1024);
    }
    __syncthreads();   // drains vmcnt(0): gload_lds landed

    #pragma unroll
    for (int kk = 0; kk < 2; ++kk) {
      s16x8 ahi[2], alo[2], bh[4], bl[4];
      #pragma unroll
      for (int rf = 0; rf < 2; ++rf) {
        const int row = wr * 32 + rf * 16 + (l & 15);
        const int gl = 8 * kk + 2 * (l >> 4);
        const int g0 = gl ^ (row & 7), g1 = (gl + 1) ^ (row & 7);
        f32x4 u0 = *(const f32x4*)((const char*)Xs + row * 256 + g0 * 16);
        f32x4 u1 = *(const f32x4*)((const char*)Xs + row * 256 + g1 * 16);
        split8(u0, u1, ahi[rf], alo[rf]);
      }
      #pragma unroll
      for (int cf = 0; cf < 4; ++cf) {
        const int col = wc * 64 + cf * 16 + (l & 15);
        const int s8 = (4 * kk + (l >> 4)) ^ (col & 7);
        bh[cf] = *(const s16x8*)((const char*)Bh + col * 128 + s8 * 16);
        bl[cf] = *(const s16x8*)((const char*)Bl + col * 128 + s8 * 16);
      }
      #pragma unroll
      for (int rf = 0; rf < 2; ++rf)
        #pragma unroll
        for (int cf = 0; cf < 4; ++cf) {
          acc[rf][cf] = MFMA_BF16(ahi[rf], bh[cf], acc[rf][cf]);
          acc[rf][cf] = MFMA_BF16(ahi[rf], bl[cf], acc[rf][cf]);
          acc[rf][cf] = MFMA_BF16(alo[rf], bh[cf], acc[rf][cf]);
        }
    }
    __syncthreads();
  }

  // epilogue: bias + relu, f32 store
  #pragma unroll
  for (int rf = 0; rf < 2; ++rf)
    #pragma unroll
    for (int cf = 0; cf < 4; ++cf)
      #pragma unroll
      for (int rg = 0; rg < 4; ++rg) {
        const int row = b0 + wr * 32 + rf * 16 + (l >> 4) * 4 + rg;
        const int col = cb * 128 + wc * 64 + cf * 16 + (l & 15);
        A1[(size_t)row * Hh + col] = fmaxf(acc[rf][cf][rg] + bs1[col], 0.f);
      }
}

// ---------------- ctrl = A1 @ Ws2 + bs2 (fallback path only)
__global__ __launch_bounds__(256) void kA2(const float* __restrict__ Ws2, const float* __restrict__ bs2,
                                           float* out)
{
  const int b0 = blockIdx.x * 64;
  __shared__ float XS[32][68];
  __shared__ float WC[32][48];
  const int tid = threadIdx.x;
  const int rg = tid >> 4, jg = tid & 15;
  float acc[4][3];
  #pragma unroll
  for (int r = 0; r < 4; ++r) { acc[r][0]=0.f; acc[r][1]=0.f; acc[r][2]=0.f; }
  const float* A1 = out;
  for (int kc = 0; kc < 8; ++kc) {
    const int k0 = kc*32;
    #pragma unroll
    for (int it = 0; it < 2; ++it) {
      int i = tid + 256*it;
      int row = i >> 3, kq = i & 7;
      float4 v = *(const float4*)&A1[(size_t)(b0+row)*Hh + k0 + 4*kq];
      XS[4*kq+0][row]=v.x; XS[4*kq+1][row]=v.y; XS[4*kq+2][row]=v.z; XS[4*kq+3][row]=v.w;
    }
    #pragma unroll
    for (int it = 0; it < 2; ++it) {
      int i = tid + 256*it;
      if (i < 384) {
        int k = i / 12, jq = i % 12;
        *(float4*)&WC[k][4*jq] = *(const float4*)&Ws2[(size_t)(k0+k)*48 + 4*jq];
      }
    }
    __syncthreads();
    #pragma unroll
    for (int k = 0; k < 32; ++k) {
      const float4 av = *(const float4*)&XS[k][rg*4];
      const float ar[4] = {av.x,av.y,av.z,av.w};
      const float w0 = WC[k][jg], w1 = WC[k][jg+16], w2 = WC[k][jg+32];
      #pragma unroll
      for (int r = 0; r < 4; ++r) {
        acc[r][0] = fmaf(ar[r], w0, acc[r][0]);
        acc[r][1] = fmaf(ar[r], w1, acc[r][1]);
        acc[r][2] = fmaf(ar[r], w2, acc[r][2]);
      }
    }
    __syncthreads();
  }
  const float c0b = bs2[jg], c1b = bs2[jg+16], c2b = bs2[jg+32];
  #pragma unroll
  for (int r = 0; r < 4; ++r) {
    size_t row = (size_t)b0 + rg*4 + r;
    out[O1 + row*NBk + jg] = acc[r][0] + c0b;
    out[O4 + row*NBk + jg] = acc[r][1] + c1b;
    out[O5 + row*NBk + jg] = acc[r][2] + c2b;
  }
}

// ---------------- kB2: element-parallel gumbel/softmax/argmax/z (fallback; reads ctrl from out)
__global__ __launch_bounds__(256) void kB2(const float* __restrict__ u, const float* __restrict__ eps,
                                           float* out, int* __restrict__ idxw, float* __restrict__ zsel,
                                           int* __restrict__ counts)
{
  const int e = blockIdx.x * 256 + threadIdx.x;
  const int b = e >> 4, j = e & 15;
  const float yl = out[O1 + e];
  const float zm = out[O4 + e];
  const float zv = out[O5 + e];
  const float s  = yl - logf(-logf(u[e]));
  const float z  = zm + expf(0.5f * zv) * eps[e];

  float bv = s; int bj = j;
  #pragma unroll
  for (int m = 8; m >= 1; m >>= 1) {
    const float ov = __shfl_xor(bv, m, 16);
    const int   oj = __shfl_xor(bj, m, 16);
    if (ov > bv || (ov == bv && oj < bj)) { bv = ov; bj = oj; }
  }
  const float ex = expf(s - bv);
  float sum = ex;
  #pragma unroll
  for (int m = 8; m >= 1; m >>= 1) sum += __shfl_xor(sum, m, 16);
  const float inv = 1.f / sum;

  out[O3 + e] = ex * inv;
  out[O6 + e] = z;
  if (j == bj) {
    out[O2 + b] = (float)bj;
    idxw[b] = bj;
    zsel[b] = z;
    atomicAdd(&counts[bj], 1);
  }
}

// ---------------- kB3: FUSED ctrl GEMM + gumbel/softmax/argmax/z, LDS-staged (v3)
// Block = 16 rows x 16 experts. A1 tile (16x256 f32) + all of Ws2T (48x256 f32)
// staged in LDS (padded rows of 258: max 2-way bank aliasing = free). fmaf chain
// reads identical values in identical ascending-k order -> bit-identical logits.
__global__ __launch_bounds__(256) void kB3(const float* __restrict__ A1, const float* __restrict__ Ws2T,
                                           const float* __restrict__ bs2,
                                           const float* __restrict__ u, const float* __restrict__ eps,
                                           float* out, int* __restrict__ idxw, float* __restrict__ zsel)
{
  __shared__ float AS[16][258];
  __shared__ float WS[48][258];
  const int tid = threadIdx.x;
  const int brow0 = blockIdx.x * 16;

  // stage A1 tile: 1024 f32x4, 4 per thread (coalesced)
  #pragma unroll
  for (int it = 0; it < 4; ++it) {
    const int i = tid + 256 * it;
    const int row = i >> 6, kq = i & 63;
    const f32x4 v = *(const f32x4*)&A1[(size_t)(brow0 + row) * Hh + kq * 4];
    *(f32x4*)&AS[row][kq * 4] = v;
  }
  // stage Ws2T: 3072 f32x4, 12 per thread (coalesced; L2-resident, 48KB)
  #pragma unroll
  for (int it = 0; it < 12; ++it) {
    const int i = tid + 256 * it;
    const int row = i >> 6, kq = i & 63;
    const f32x4 v = *(const f32x4*)&Ws2T[(size_t)row * Hh + kq * 4];
    *(f32x4*)&WS[row][kq * 4] = v;
  }
  __syncthreads();

  const int e = blockIdx.x * 256 + tid;
  const int b = e >> 4, j = tid & 15;
  const int rl = tid >> 4;

  float c0 = 0.f, c1 = 0.f, c2 = 0.f;
  #pragma unroll 4
  for (int k = 0; k < Hh; k += 4) {
    const f32x4 av = *(const f32x4*)&AS[rl][k];      // same-addr broadcast in 16-lane group
    const f32x4 wa = *(const f32x4*)&WS[j][k];
    const f32x4 wb = *(const f32x4*)&WS[j + 16][k];
    const f32x4 wc = *(const f32x4*)&WS[j + 32][k];
    #pragma unroll
    for (int kk = 0; kk < 4; ++kk) {   // ascending k: bit-identical to kA2's chain
      c0 = fmaf(av[kk], wa[kk], c0);
      c1 = fmaf(av[kk], wb[kk], c1);
      c2 = fmaf(av[kk], wc[kk], c2);
    }
  }
  const float yl = c0 + bs2[j];
  const float zm = c1 + bs2[j + 16];
  const float zv = c2 + bs2[j + 32];

  const float s = yl - logf(-logf(u[e]));
  const float z = zm + expf(0.5f * zv) * eps[e];

  float bv = s; int bj = j;
  #pragma unroll
  for (int m = 8; m >= 1; m >>= 1) {
    const float ov = __shfl_xor(bv, m, 16);
    const int   oj = __shfl_xor(bj, m, 16);
    if (ov > bv || (ov == bv && oj < bj)) { bv = ov; bj = oj; }
  }
  const float ex = expf(s - bv);
  float sum = ex;
  #pragma unroll
  for (int m = 8; m >= 1; m >>= 1) sum += __shfl_xor(sum, m, 16);
  const float inv = 1.f / sum;

  out[O1 + e] = yl;
  out[O4 + e] = zm;
  out[O5 + e] = zv;
  out[O3 + e] = ex * inv;
  out[O6 + e] = z;
  if (j == bj) {
    out[O2 + b] = (float)bj;
    idxw[b] = bj;
    zsel[b] = z;
  }
}

// ---------------- kH: expert histogram, block-aggregated (64 blocks -> 1024 global atomics)
__global__ __launch_bounds__(256) void kH(const int* __restrict__ idxw, int* __restrict__ counts)
{
  __shared__ int lh[NBk];
  const int tid = threadIdx.x;
  if (tid < NBk) lh[tid] = 0;
  __syncthreads();
  atomicAdd(&lh[idxw[blockIdx.x * 256 + tid]], 1);
  __syncthreads();
  if (tid < NBk && lh[tid]) atomicAdd(&counts[tid], lh[tid]);
}

// ---------------- prefix sums over 16 experts (+ tile prefixes and 128-aligned h segments)
__global__ void kP(const int* __restrict__ counts, int* __restrict__ offs, int* __restrict__ cursor,
                   int* __restrict__ bpre, int* __restrict__ tp1, int* __restrict__ tp2,
                   int* __restrict__ seg)
{
  if (threadIdx.x == 0 && blockIdx.x == 0) {
    int a = 0, bb = 0, t1 = 0, t2 = 0, sg = 0;
    for (int n = 0; n < NBk; ++n) {
      offs[n] = a; cursor[n] = a; bpre[n] = bb; tp1[n] = t1; tp2[n] = t2; seg[n] = sg;
      const int c = counts[n];
      a  += c;
      bb += (c + 31) >> 5;
      t1 += (c + 63) >> 6;
      t2 += (c + 127) >> 7;
      sg += ((c + 127) >> 7) * 128;
    }
    offs[NBk] = a; bpre[NBk] = bb; tp1[NBk] = t1; tp2[NBk] = t2; seg[NBk] = sg;
  }
}

// ---------------- kS: per-row scatter (fallback paths; 16384 cursor atomics)
__global__ __launch_bounds__(256) void kS(const int* __restrict__ idxw, int* __restrict__ cursor,
                                          int* __restrict__ rowlist)
{
  const int b = blockIdx.x * 256 + threadIdx.x;
  const int n = idxw[b];
  const int pos = atomicAdd(&cursor[n], 1);
  rowlist[pos] = b;
}

// ---------------- kS2: block-aggregated scatter (64 blocks -> 1024 cursor atomics)
__global__ __launch_bounds__(256) void kS2(const int* __restrict__ idxw, int* __restrict__ cursor,
                                           int* __restrict__ rowlist)
{
  __shared__ int lh[NBk];
  __shared__ int gb[NBk];
  const int tid = threadIdx.x;
  const int b = blockIdx.x * 256 + tid;
  const int n = idxw[b];
  if (tid < NBk) lh[tid] = 0;
  __syncthreads();
  const int rank = atomicAdd(&lh[n], 1);
  __syncthreads();
  if (tid < NBk) gb[tid] = lh[tid] ? atomicAdd(&cursor[tid], lh[tid]) : 0;
  __syncthreads();
  rowlist[gb[n] + rank] = b;
}

// ---------------- transpose + convert: in [n][R][C] f32 -> out [n][C][R] bf16
__global__ __launch_bounds__(256) void kT(const float* __restrict__ in, unsigned short* __restrict__ out,
                                          int R, int C)
{
  const int n = blockIdx.z;
  in  += (size_t)n * R * C;
  out += (size_t)n * R * C;
  const int i0 = blockIdx.x * 32, j0 = blockIdx.y * 32;
  __shared__ float T[32][33];
  const int t = threadIdx.x;
  {
    const int ii = t >> 3, jj = (t & 7) * 4;
    float4 v = *(const float4*)&in[(size_t)(i0+ii)*C + j0 + jj];
    T[ii][jj] = v.x; T[ii][jj+1] = v.y; T[ii][jj+2] = v.z; T[ii][jj+3] = v.w;
  }
  __syncthreads();
  {
    const int jo = t >> 3, io = (t & 7) * 4;
    ushort4 st;
    st.x = f2b(T[io+0][jo]);
    st.y = f2b(T[io+1][jo]);
    st.z = f2b(T[io+2][jo]);
    st.w = f2b(T[io+3][jo]);
    *(ushort4*)&out[(size_t)(j0+jo)*R + i0 + io] = st;
  }
}

// ================= kG1: h = relu(x @ W1[n] + b1)*z  (ROUND-4 PROVEN FORM: gload_lds)
__global__ __launch_bounds__(256) void kG1(const float* __restrict__ x,
    const unsigned short* __restrict__ W1T, const float* __restrict__ b1,
    const int* __restrict__ rowlist, const float* __restrict__ zsel,
    const int* __restrict__ offs, const int* __restrict__ tp1, const int* __restrict__ seg,
    unsigned short* __restrict__ hbuf)
{
  __shared__ __align__(16) float Xs[64*64];
  __shared__ __align__(16) unsigned short Wsh[128*64];
  __shared__ int rows_s[64];
  __shared__ float zrs[64];

  const int bid = blockIdx.x;
  const int tile = bid >> 1, cb = bid & 1;
  if (tile >= tp1[NBk]) return;
  int n = 0;
  while (tile >= tp1[n+1]) ++n;
  const int tt = tile - tp1[n];
  const int base = offs[n], cnt = offs[n+1] - base;
  const int r0 = tt * 64;
  const int tid = threadIdx.x, l = tid & 63, w = tid >> 6;
  const int wr = w >> 1, wc = w & 1;

  if (tid < 64) {
    int r = r0 + tid;
    int g = rowlist[base + (r < cnt ? r : cnt - 1)];
    rows_s[tid] = g;
    zrs[tid] = zsel[g];
  }
  __syncthreads();

  size_t xsrc[4];
  const unsigned short* wsrc[4];
  const unsigned short* Wbase = W1T + (size_t)n * (Hh * Dd) + (size_t)(cb * 128) * Dd;
  #pragma unroll
  for (int t = 0; t < 4; ++t) {
    {
      int row = (w * 4 + t) * 4 + (l >> 4);
      int ga = (l & 15) ^ (row & 7);
      xsrc[t] = (size_t)rows_s[row] * Dd + ga * 4;
    }
    {
      int row = (w * 4 + t) * 8 + (l >> 3);
      int sa = (l & 7) ^ (row & 7);
      wsrc[t] = Wbase + (size_t)row * Dd + sa * 8;
    }
  }

  f32x4 acc[2][4];
  #pragma unroll
  for (int a = 0; a < 2; ++a)
    #pragma unroll
    for (int b_ = 0; b_ < 4; ++b_)
      #pragma unroll
      for (int e = 0; e < 4; ++e) acc[a][b_][e] = 0.f;

  for (int kc = 0; kc < 16; ++kc) {
    #pragma unroll
    for (int t = 0; t < 4; ++t) {
      gload16(&x[xsrc[t] + kc * 64], (char*)Xs + (w * 4 + t) * 1024);
      gload16(wsrc[t] + kc * 64, (char*)Wsh + (w * 4 + t) * 1024);
    }
    __syncthreads();

    #pragma unroll
    for (int kk = 0; kk < 2; ++kk) {
      s16x8 af[2], bf[4];
      #pragma unroll
      for (int rf = 0; rf < 2; ++rf) {
        const int row = wr * 32 + rf * 16 + (l & 15);
        const int gl = 8 * kk + 2 * (l >> 4);
        const int g0 = gl ^ (row & 7), g1 = (gl + 1) ^ (row & 7);
        f32x4 u0 = *(const f32x4*)((const char*)Xs + row * 256 + g0 * 16);
        f32x4 u1 = *(const f32x4*)((const char*)Xs + row * 256 + g1 * 16);
        af[rf] = cvt8(u0, u1);
      }
      #pragma unroll
      for (int cf = 0; cf < 4; ++cf) {
        const int col = wc * 64 + cf * 16 + (l & 15);
        const int s8 = (4 * kk + (l >> 4)) ^ (col & 7);
        bf[cf] = *(const s16x8*)((const char*)Wsh + col * 128 + s8 * 16);
      }
      #pragma unroll
      for (int rf = 0; rf < 2; ++rf)
        #pragma unroll
        for (int cf = 0; cf < 4; ++cf)
          acc[rf][cf] = MFMA_BF16(af[rf], bf[cf], acc[rf][cf]);
    }
    __syncthreads();
  }

  const size_t hrow0 = (size_t)seg[n] + r0;
  #pragma unroll
  for (int rf = 0; rf < 2; ++rf)
    #pragma unroll
    for (int cf = 0; cf < 4; ++cf)
      #pragma unroll
      for (int rg = 0; rg < 4; ++rg) {
        const int rloc = wr * 32 + rf * 16 + (l >> 4) * 4 + rg;
        const int col = cb * 128 + wc * 64 + cf * 16 + (l & 15);
        const float hv = fmaxf(acc[rf][cf][rg] + b1[n * Hh + col], 0.f) * zrs[rloc];
        hbuf[(hrow0 + rloc) * Hh + col] = f2b(hv);
      }
}

// ================= kG2: out = h @ W2[n] + b2 + x  (128-row x 128-col tiles, 8 col-blocks)
__global__ __launch_bounds__(256) void kG2(const float* __restrict__ x,
    const unsigned short* __restrict__ W2T, const float* __restrict__ b2,
    const unsigned short* __restrict__ hbuf, const int* __restrict__ rowlist,
    const int* __restrict__ offs, const int* __restrict__ tp2, const int* __restrict__ seg,
    float* __restrict__ out)
{
  __shared__ __align__(16) unsigned short As[128*64];
  __shared__ __align__(16) unsigned short Bs[128*64];
  __shared__ int rows_s[128];

  const int bid = blockIdx.x;
  const int tile = bid >> 3, cb = bid & 7;
  if (tile >= tp2[NBk]) return;
  int n = 0;
  while (tile >= tp2[n+1]) ++n;
  const int tt = tile - tp2[n];
  const int base = offs[n], cnt = offs[n+1] - base;
  const int r0 = tt * 128;
  const int tid = threadIdx.x, l = tid & 63, w = tid >> 6;
  const int wr = w >> 1, wc = w & 1;

  if (tid < 128) {
    int r = r0 + tid;
    rows_s[tid] = rowlist[base + (r < cnt ? r : cnt - 1)];
  }
  __syncthreads();

  const unsigned short* Abase = hbuf + (size_t)(seg[n] + r0) * Hh;
  const unsigned short* Bbase = W2T + (size_t)n * (Hh * Dd) + (size_t)(cb * 128) * Hh;

  const unsigned short* asrc[4];
  const unsigned short* bsrc[4];
  #pragma unroll
  for (int t = 0; t < 4; ++t) {
    const int row = (w * 4 + t) * 8 + (l >> 3);
    const int sa = (l & 7) ^ (row & 7);
    asrc[t] = Abase + (size_t)row * Hh + sa * 8;
    bsrc[t] = Bbase + (size_t)row * Hh + sa * 8;
  }

  f32x4 acc[4][4];
  #pragma unroll
  for (int a = 0; a < 4; ++a)
    #pragma unroll
    for (int b_ = 0; b_ < 4; ++b_)
      #pragma unroll
      for (int e = 0; e < 4; ++e) acc[a][b_][e] = 0.f;

  for (int kc = 0; kc < 4; ++kc) {
    #pragma unroll
    for (int t = 0; t < 4; ++t) {
      gload16(asrc[t] + kc * 64, (char*)As + (w * 4 + t) * 1024);
      gload16(bsrc[t] + kc * 64, (char*)Bs + (w * 4 + t) * 1024);
    }
    __syncthreads();

    #pragma unroll
    for (int kk = 0; kk < 2; ++kk) {
      s16x8 af[4], bf[4];
      #pragma unroll
      for (int rf = 0; rf < 4; ++rf) {
        const int row = wr * 64 + rf * 16 + (l & 15);
        const int s8 = (4 * kk + (l >> 4)) ^ (row & 7);
        af[rf] = *(const s16x8*)((const char*)As + row * 128 + s8 * 16);
      }
      #pragma unroll
      for (int cf = 0; cf < 4; ++cf) {
        const int col = wc * 64 + cf * 16 + (l & 15);
        const int s8 = (4 * kk + (l >> 4)) ^ (col & 7);
        bf[cf] = *(const s16x8*)((const char*)Bs + col * 128 + s8 * 16);
      }
      #pragma unroll
      for (int rf = 0; rf < 4; ++rf)
        #pragma unroll
        for (int cf = 0; cf < 4; ++cf)
          acc[rf][cf] = MFMA_BF16(af[rf], bf[cf], acc[rf][cf]);
    }
    __syncthreads();
  }

  #pragma unroll
  for (int rf = 0; rf < 4; ++rf)
    #pragma unroll
    for (int rg = 0; rg < 4; ++rg) {
      const int rloc = wr * 64 + rf * 16 + (l >> 4) * 4 + rg;
      if (r0 + rloc < cnt) {
        const int g = rows_s[rloc];
        #pragma unroll
        for (int cf = 0; cf < 4; ++cf) {
          const int col = cb * 128 + wc * 64 + cf * 16 + (l & 15);
          out[(size_t)g * Dd + col] = acc[rf][cf][rg] + b2[n * Dd + col] + x[(size_t)g * Dd + col];
        }
      }
    }
}

extern "C" void kernel_launch(void* const* d_in, const int* in_sizes, int n_in,
                              void* d_out, int out_size, void* d_ws, size_t ws_size,
                              hipStream_t stream) {
  const float* x   = (const float*)d_in[0];
  const float* Ws1 = (const float*)d_in[1];
  const float* bs1 = (const float*)d_in[2];
  const float* Ws2 = (const float*)d_in[3];
  const float* bs2 = (const float*)d_in[4];
  const float* W1  = (const float*)d_in[5];
  const float* b1  = (const float*)d_in[6];
  const float* W2  = (const float*)d_in[7];
  const float* b2  = (const float*)d_in[8];
  const float* u   = (const float*)d_in[9];
  const float* eps = (const float*)d_in[10];
  float* out = (float*)d_out;

  char* ws = (char*)d_ws;
  int*   counts  = (int*)(ws + 0);
  int*   cursor  = (int*)(ws + 64);
  int*   bpre    = (int*)(ws + 128);
  int*   offs    = (int*)(ws + 256);
  int*   tp1     = (int*)(ws + 384);
  int*   tp2     = (int*)(ws + 512);
  int*   seg     = (int*)(ws + 640);
  int*   idxw    = (int*)(ws + 4096);
  float* zsel    = (float*)(ws + 4096 + 65536);
  int*   rowlist = (int*)(ws + 4096 + 131072);
  float* Ws2T    = (float*)(ws + 786432);                             // [48][256] f32 = 48KB
  unsigned short* W1T  = (unsigned short*)(ws + ((size_t)1 << 20));   // [16][256][1024] bf16 = 8MB
  unsigned short* W2T  = (unsigned short*)(ws + ((size_t)9 << 20));   // [16][1024][256] bf16 = 8MB
  unsigned short* hbuf = (unsigned short*)(ws + ((size_t)17 << 20));  // [<=18432][256] bf16 = 9.44MB
  unsigned short* Whi  = (unsigned short*)(ws + ((size_t)27 << 20));  // [256][1024] bf16 = 512KB
  unsigned short* Wlo  = (unsigned short*)(ws + ((size_t)27 << 20) + (512<<10)); // 512KB

  const bool f2 = ws_size >= ((size_t)28 << 20);
  const bool f1 = ws_size >= ((size_t)18 << 20);

  hipMemsetAsync(d_ws, 0, 4096, stream);
  if (f1 || f2) {
    kT<<<dim3(32, 8, 16), 256, 0, stream>>>(W1, W1T, Dd, Hh);   // -> [n][h][d]
    kT<<<dim3(8, 32, 16), 256, 0, stream>>>(W2, W2T, Hh, Dd);   // -> [n][d][h]
  }
  if (f2) {
    kTW<<<dim3(32, 8), 256, 0, stream>>>(Ws1, Whi, Wlo);        // Ws1^T hi/lo bf16
    kT2<<<dim3(48), 256, 0, stream>>>(Ws2, Ws2T);               // Ws2^T f32
    kA1s<<<dim3(512), 256, 0, stream>>>(x, Whi, Wlo, bs1, out); // A1 via split-bf16 MFMA
    kB3<<<dim3(Bn/16), 256, 0, stream>>>(out, Ws2T, bs2, u, eps, out, idxw, zsel);
    kH <<<dim3(Bn/256), 256, 0, stream>>>(idxw, counts);        // block-aggregated counts
  } else {
    kA1<<<dim3(Bn/64, 2), 256, 0, stream>>>(x, Ws1, bs1, out);
    kA2<<<dim3(Bn/64), 256, 0, stream>>>(Ws2, bs2, out);
    kB2<<<dim3(Bn*NBk/256), 256, 0, stream>>>(u, eps, out, idxw, zsel, counts);
  }
  kP <<<dim3(1), 64, 0, stream>>>(counts, offs, cursor, bpre, tp1, tp2, seg);
  if (f2) {
    kS2<<<dim3(Bn/256), 256, 0, stream>>>(idxw, cursor, rowlist); // block-aggregated scatter
    kG1<<<dim3(544), 256, 0, stream>>>(x, W1T, b1, rowlist, zsel, offs, tp1, seg, hbuf);
    kG2<<<dim3(1152), 256, 0, stream>>>(x, W2T, b2, hbuf, rowlist, offs, tp2, seg, out);
  } else {
    kS<<<dim3(Bn/256), 256, 0, stream>>>(idxw, cursor, rowlist);
  }
}